// Round 6
// baseline (211.647 us; speedup 1.0000x reference)
//
#include <hip/hip_runtime.h>
#include <math.h>
#include <stdint.h>

#define B_ 4096
#define T_ 128
#define S_ 16
#define C_ 128
#define L_ 33            // 2*S+1
#define NSLOT 17         // blank + 16 targets
#define NELEM (T_ * NSLOT)    // 2176 = 34 * 64
#define LDSF  (NELEM + 64)    // pad: prefetch ring reads to idx 130*17+16 = 2226
#define NEGV (-1e30f)
#define LOG2E 1.4426950408889634f
#define LN2 0.6931471805599453f
#define NEGB (NEGV * LOG2E)

__device__ __forceinline__ float hexp2(float x) { return __builtin_amdgcn_exp2f(x); }
__device__ __forceinline__ float hlog2(float x) { return __builtin_amdgcn_logf(x); }

// monotonic float->uint map: a > b (float) <=> fkey(a) > fkey(b) (uint)
__device__ __forceinline__ unsigned fkey(float v) {
    unsigned u = __float_as_uint(v);
    return (u & 0x80000000u) ? ~u : (u | 0x80000000u);
}

typedef const __attribute__((address_space(1))) unsigned int* gas_t;
typedef __attribute__((address_space(3))) unsigned int* las_t;

// 4 waves per block, one batch element per wave; no inter-wave communication.
// Last-finishing wave (device-wide counter) does the deterministic mean.
__global__ __launch_bounds__(256) void ctc_fused_kernel(
        const float* __restrict__ pred,   // (B, T, C) log-probs
        const float* __restrict__ lab,    // (B, S, C)
        float* __restrict__ out_b,        // ws[0..B): nll/S per element
        int* __restrict__ counter,        // ws + B, zeroed per call (memset node)
        float* __restrict__ out) {        // d_out[0]
    const int wid  = threadIdx.x >> 6;
    const int lane = threadIdx.x & 63;
    const int b = blockIdx.x * 4 + wid;

    __shared__ int   cls_tab[4][NSLOT];
    __shared__ float lps[4][LDSF];        // flat [t*17 + slot], per wave

    // ---- Phase A: targets[s] = argmax_c lab[b,s,c], first-index tie-break ----
    // Two rows per pass (lanes 0-31 row 2sp, lanes 32-63 row 2sp+1), float4 loads.
    const int half = lane >> 5;
    const int li   = lane & 31;
    const float4* lrow4 =
        (const float4*)(lab + (size_t)b * S_ * C_ + (size_t)half * C_);
    float4 q[8];
    #pragma unroll
    for (int sp = 0; sp < 8; ++sp)
        q[sp] = lrow4[(size_t)sp * 2 * (C_ / 4) + li];   // 8 indep 16B loads

    if (lane == 0) cls_tab[wid][0] = 0;   // blank class
    #pragma unroll
    for (int sp = 0; sp < 8; ++sp) {
        float vals[4] = {q[sp].x, q[sp].y, q[sp].z, q[sp].w};
        unsigned long long key = 0;       // fkey(v)<<32 | ~idx : max == (max v, min idx)
        #pragma unroll
        for (int k = 0; k < 4; ++k) {
            unsigned long long kk =
                ((unsigned long long)fkey(vals[k]) << 32) | (unsigned)(~(li * 4 + k));
            if (kk > key) key = kk;       // strict >, k ascending: first index wins
        }
        #pragma unroll
        for (int off = 16; off >= 1; off >>= 1) {
            unsigned long long ok = __shfl_xor(key, off, 64);  // stays within half
            if (ok > key) key = ok;
        }
        if (li == 0) cls_tab[wid][1 + sp * 2 + half] = (int)(~(unsigned)key) & 127;
    }
    asm volatile("s_waitcnt lgkmcnt(0)" ::: "memory");   // cls_tab visible in-wave

    // ---- Phase B: stage lp[t][slot] into LDS, two 64-timestep chunks ----
    // e = i*64+lane -> t = e/17, slot = e%17; LDS dest linear in lane.
    const float* pb = pred + (size_t)b * T_ * C_;
    float* mylds = lps[wid];
    #pragma unroll
    for (int i = 0; i < 17; ++i) {        // chunk A: t in [0,64)
        unsigned e = i * 64 + lane;
        unsigned t = e / NSLOT;
        unsigned s = e - t * NSLOT;
        const float* src = pb + (size_t)t * C_ + cls_tab[wid][s];
        __builtin_amdgcn_global_load_lds((gas_t)src, (las_t)(mylds + i * 64), 4, 0, 0);
    }
    __builtin_amdgcn_sched_barrier(0);    // pin issue order: A fully before B
    #pragma unroll
    for (int i = 17; i < 34; ++i) {       // chunk B: t in [64,128)
        unsigned e = i * 64 + lane;
        unsigned t = e / NSLOT;
        unsigned s = e - t * NSLOT;
        const float* src = pb + (size_t)t * C_ + cls_tab[wid][s];
        __builtin_amdgcn_global_load_lds((gas_t)src, (las_t)(mylds + i * 64), 4, 0, 0);
    }
    __builtin_amdgcn_sched_barrier(0);

    // ---- Phase C: alpha recursion in log2 domain ----
    const int l = lane;
    int cidx = 0;
    bool skipv = false;
    if (l < L_ && (l & 1)) {
        cidx = 1 + ((l - 1) >> 1);
        if (l >= 3) skipv = (cls_tab[wid][cidx] != cls_tab[wid][cidx - 1]);
    }
    const bool has2 = (l >= 1);

    asm volatile("s_waitcnt vmcnt(17)" ::: "memory");    // chunk A ready

    float beta = (l <= 1) ? mylds[cidx] * LOG2E : NEGB;  // t = 0
    float lpA = mylds[1 * NSLOT + cidx];
    float lpB = mylds[2 * NSLOT + cidx];
    float lpC = mylds[3 * NSLOT + cidx];

    #pragma unroll 4
    for (int t = 1; t <= 60; ++t) {       // reads up to (63)*17: chunk A only
        float lp = lpA; lpA = lpB; lpB = lpC;
        lpC = mylds[(t + 3) * NSLOT + cidx];
        float a2 = __shfl_up(beta, 1, 64);
        float a3 = __shfl_up(beta, 2, 64);
        a2 = has2  ? a2 : NEGB;
        a3 = skipv ? a3 : NEGB;
        float m = fmaxf(fmaxf(beta, a2), a3);            // v_max3_f32
        float s = hexp2(beta - m) + hexp2(a2 - m) + hexp2(a3 - m);
        beta = fmaf(lp, LOG2E, m + hlog2(s));
    }

    asm volatile("s_waitcnt vmcnt(0)" ::: "memory");     // chunk B ready

    #pragma unroll 4
    for (int t = 61; t < T_; ++t) {       // pad covers reads to t+3 = 130
        float lp = lpA; lpA = lpB; lpB = lpC;
        lpC = mylds[(t + 3) * NSLOT + cidx];
        float a2 = __shfl_up(beta, 1, 64);
        float a3 = __shfl_up(beta, 2, 64);
        a2 = has2  ? a2 : NEGB;
        a3 = skipv ? a3 : NEGB;
        float m = fmaxf(fmaxf(beta, a2), a3);
        float s = hexp2(beta - m) + hexp2(a2 - m) + hexp2(a3 - m);
        beta = fmaf(lp, LOG2E, m + hlog2(s));
    }

    float b31 = __shfl(beta, L_ - 2, 64);
    float b32 = __shfl(beta, L_ - 1, 64);
    float m2 = fmaxf(b31, b32);
    float nll = -(m2 + hlog2(hexp2(b31 - m2) + hexp2(b32 - m2))) * LN2;
    if (!isfinite(nll)) nll = 0.0f;       // zero_infinity
    float val = nll * (1.0f / (float)S_);
    if (lane == 0)
        __hip_atomic_store(&out_b[b], val, __ATOMIC_RELAXED, __HIP_MEMORY_SCOPE_AGENT);

    // ---- Phase D: last-arriving WAVE does the deterministic mean ----
    int old = 0;
    if (lane == 0)
        old = __hip_atomic_fetch_add(counter, 1, __ATOMIC_ACQ_REL,
                                     __HIP_MEMORY_SCOPE_AGENT);
    old = __shfl(old, 0, 64);
    if (old == B_ - 1) {                  // exactly one wave; result is
        __threadfence();                  // wave-identity-independent
        float s = 0.f;
        #pragma unroll 16
        for (int i = 0; i < B_ / 64; ++i) // fixed order: deterministic
            s += __hip_atomic_load(&out_b[lane + i * 64], __ATOMIC_RELAXED,
                                   __HIP_MEMORY_SCOPE_AGENT);
        #pragma unroll
        for (int off = 1; off < 64; off <<= 1)
            s += __shfl_xor(s, off, 64);  // fixed butterfly order
        if (lane == 0) *out = s * (1.0f / (float)B_);
    }
}

extern "C" void kernel_launch(void* const* d_in, const int* in_sizes, int n_in,
                              void* d_out, int out_size, void* d_ws, size_t ws_size,
                              hipStream_t stream) {
    const float* pred = (const float*)d_in[0];  // (B,T,C) fp32
    const float* lab  = (const float*)d_in[1];  // (B,S,C) fp32
    float* ws = (float*)d_ws;                   // [0,B): partials; +B: counter
    int* counter = (int*)(ws + B_);
    hipMemsetAsync(counter, 0, sizeof(int), stream);   // graph-capturable memset node
    ctc_fused_kernel<<<B_ / 4, 256, 0, stream>>>(pred, lab, ws, counter, (float*)d_out);
}

// Round 7
// 65.815 us; speedup vs baseline: 3.2158x; 3.2158x over previous
//
#include <hip/hip_runtime.h>
#include <math.h>
#include <stdint.h>

#define B_ 4096
#define T_ 128
#define S_ 16
#define C_ 128
#define L_ 33            // 2*S+1
#define NSLOT 17         // blank + 16 targets
#define NELEM (T_ * NSLOT)    // 2176 = 34 * 64
#define LDSF  (NELEM + 64)    // pad: prefetch ring reads to idx 130*17+16 = 2226
#define NWAVE 2048            // waves; each does 2 batch elements
#define NEGV (-1e30f)
#define LOG2E 1.4426950408889634f
#define LN2 0.6931471805599453f
#define NEGB (NEGV * LOG2E)

__device__ __forceinline__ float hexp2(float x) { return __builtin_amdgcn_exp2f(x); }
__device__ __forceinline__ float hlog2(float x) { return __builtin_amdgcn_logf(x); }

// monotonic float->uint map: a > b (float) <=> fkey(a) > fkey(b) (uint)
__device__ __forceinline__ unsigned fkey(float v) {
    unsigned u = __float_as_uint(v);
    return (u & 0x80000000u) ? ~u : (u | 0x80000000u);
}

typedef const __attribute__((address_space(1))) unsigned int* gas_t;
typedef __attribute__((address_space(3))) unsigned int* las_t;

// 4 waves/block, each wave pipelines TWO batch elements (b, b+NWAVE).
// No atomics, no inter-wave communication. Plain stores to ws partials.
__global__ __launch_bounds__(256) void ctc_main_kernel(
        const float* __restrict__ pred,   // (B, T, C) log-probs
        const float* __restrict__ lab,    // (B, S, C)
        float* __restrict__ out_b) {      // ws[0..B): nll/S per element
    const int wid  = threadIdx.x >> 6;
    const int lane = threadIdx.x & 63;
    const int w = blockIdx.x * 4 + wid;
    const int b0 = w, b1 = w + NWAVE;

    __shared__ int   cls_tab[4][NSLOT];
    __shared__ float lps[4][LDSF];        // flat [t*17 + slot], per wave
    int*   mytab = cls_tab[wid];
    float* mylds = lps[wid];

    const int half = lane >> 5;           // argmax: lanes 0-31 row 2sp, 32-63 row 2sp+1
    const int li   = lane & 31;

    // lane -> DP state constants
    const int l = lane;
    int cidx = 0;
    if (l < L_ && (l & 1)) cidx = 1 + ((l - 1) >> 1);
    const bool has2 = (l >= 1);
    const bool odd3 = (l < L_ && (l & 1) && l >= 3);

    float4 q[8];
    auto load_lab = [&](int b) {
        const float4* lr = (const float4*)(lab + (size_t)b * S_ * C_ + (size_t)half * C_);
        #pragma unroll
        for (int sp = 0; sp < 8; ++sp)
            q[sp] = lr[(size_t)sp * 2 * (C_ / 4) + li];   // 8 indep 16B loads
    };
    auto argmax_tab = [&]() {             // q -> mytab[0..16]
        if (lane == 0) mytab[0] = 0;      // blank class
        #pragma unroll
        for (int sp = 0; sp < 8; ++sp) {
            float vals[4] = {q[sp].x, q[sp].y, q[sp].z, q[sp].w};
            unsigned long long key = 0;   // fkey(v)<<32 | ~idx: max == (max v, min idx)
            #pragma unroll
            for (int k = 0; k < 4; ++k) {
                unsigned long long kk =
                    ((unsigned long long)fkey(vals[k]) << 32) | (unsigned)(~(li * 4 + k));
                if (kk > key) key = kk;   // strict >, k ascending: first index wins
            }
            #pragma unroll
            for (int off = 16; off >= 1; off >>= 1) {
                unsigned long long ok = __shfl_xor(key, off, 64);  // within half
                if (ok > key) key = ok;
            }
            if (li == 0) mytab[1 + sp * 2 + half] = (int)(~(unsigned)key) & 127;
        }
        asm volatile("s_waitcnt lgkmcnt(0)" ::: "memory");
    };
    auto stage = [&](const float* pb, int i0, int i1) {    // 17 x 4B global->LDS
        for (int i = i0; i < i1; ++i) {
            unsigned e = i * 64 + lane;
            unsigned t = e / NSLOT;
            unsigned s = e - t * NSLOT;
            const float* src = pb + (size_t)t * C_ + mytab[s];
            __builtin_amdgcn_global_load_lds((gas_t)src, (las_t)(mylds + i * 64), 4, 0, 0);
        }
        __builtin_amdgcn_sched_barrier(0);                 // pin issue order
    };

    float beta, lpA, lpB, lpC;
    bool skipv;
    auto ring_init = [&]() {
        beta = (l <= 1) ? mylds[cidx] * LOG2E : NEGB;      // t = 0
        lpA = mylds[1 * NSLOT + cidx];
        lpB = mylds[2 * NSLOT + cidx];
        lpC = mylds[3 * NSLOT + cidx];
    };
#define SEG(T0, T1)                                                         \
    _Pragma("unroll 4")                                                     \
    for (int t = (T0); t <= (T1); ++t) {                                    \
        float lp = lpA; lpA = lpB; lpB = lpC;                               \
        lpC = mylds[(t + 3) * NSLOT + cidx];                                \
        float a2 = __shfl_up(beta, 1, 64);                                  \
        float a3 = __shfl_up(beta, 2, 64);                                  \
        a2 = has2  ? a2 : NEGB;                                             \
        a3 = skipv ? a3 : NEGB;                                             \
        float m = fmaxf(fmaxf(beta, a2), a3);                               \
        float s = hexp2(beta - m) + hexp2(a2 - m) + hexp2(a3 - m);          \
        beta = fmaf(lp, LOG2E, m + hlog2(s));                               \
    }
    auto finish = [&](int b) {            // logaddexp of last two states -> ws
        float b31 = __shfl(beta, L_ - 2, 64);
        float b32 = __shfl(beta, L_ - 1, 64);
        float m2 = fmaxf(b31, b32);
        float nll = -(m2 + hlog2(hexp2(b31 - m2) + hexp2(b32 - m2))) * LN2;
        if (!isfinite(nll)) nll = 0.0f;   // zero_infinity
        if (lane == 0) out_b[b] = nll * (1.0f / (float)S_);
    };

    const float* pb0 = pred + (size_t)b0 * T_ * C_;
    const float* pb1 = pred + (size_t)b1 * T_ * C_;

    // ---------------- element 0 prologue ----------------
    load_lab(b0);                                          // out: 8
    asm volatile("s_waitcnt vmcnt(0)" ::: "memory");
    argmax_tab();
    bool skip0 = odd3 && (mytab[cidx] != mytab[cidx - 1]);
    stage(pb0, 0, 17);                                     // A0 -> buf0   out: 17
    stage(pb0, 17, 34);                                    // B0 -> buf1   out: 34
    load_lab(b1);                                          // lab1         out: 42
    __builtin_amdgcn_sched_barrier(0);

    asm volatile("s_waitcnt vmcnt(25)" ::: "memory");      // A0 ready
    ring_init();
    skipv = skip0;
    SEG(1, 60)                                             // chunk A of elem0

    asm volatile("s_waitcnt vmcnt(0)" ::: "memory");       // B0 + lab1 ready
    argmax_tab();                                          // elem1 targets
    bool skip1 = odd3 && (mytab[cidx] != mytab[cidx - 1]);
    stage(pb1, 0, 17);                                     // A1 -> buf0   out: 17
    SEG(61, 127)                                           // chunk B of elem0 (buf1); A1 in flight
    finish(b0);

    stage(pb1, 17, 34);                                    // B1 -> buf1   out: 34
    asm volatile("s_waitcnt vmcnt(17)" ::: "memory");      // A1 ready
    ring_init();
    skipv = skip1;
    SEG(1, 60)                                             // chunk A of elem1; B1 in flight

    asm volatile("s_waitcnt vmcnt(0)" ::: "memory");       // B1 ready
    SEG(61, 127)                                           // chunk B of elem1
    finish(b1);
#undef SEG
}

__global__ __launch_bounds__(256) void reduce_mean_kernel(
        const float* __restrict__ in, float* __restrict__ out) {
    __shared__ float sm[256];
    const int tid = threadIdx.x;
    float v[16];
    #pragma unroll
    for (int i = 0; i < 16; ++i) v[i] = in[tid + i * 256];
    float s = 0.f;
    #pragma unroll
    for (int i = 0; i < 16; ++i) s += v[i];
    sm[tid] = s;
    __syncthreads();
    for (int w = 128; w >= 1; w >>= 1) {
        if (tid < w) sm[tid] += sm[tid + w];
        __syncthreads();
    }
    if (tid == 0) out[0] = sm[0] / (float)B_;
}

extern "C" void kernel_launch(void* const* d_in, const int* in_sizes, int n_in,
                              void* d_out, int out_size, void* d_ws, size_t ws_size,
                              hipStream_t stream) {
    const float* pred = (const float*)d_in[0];  // (B,T,C) fp32
    const float* lab  = (const float*)d_in[1];  // (B,S,C) fp32
    float* ws = (float*)d_ws;                   // B partial losses
    ctc_main_kernel<<<NWAVE / 4, 256, 0, stream>>>(pred, lab, ws);
    reduce_mean_kernel<<<1, 256, 0, stream>>>(ws, (float*)d_out);
}

// Round 8
// 61.760 us; speedup vs baseline: 3.4269x; 1.0656x over previous
//
#include <hip/hip_runtime.h>
#include <math.h>
#include <stdint.h>

#define B_ 4096
#define T_ 128
#define S_ 16
#define C_ 128
#define L_ 33            // 2*S+1
#define NSLOT 17         // blank + 16 targets
#define CH_ROWS 32       // timesteps per staging chunk
#define CH_FLOATS 544    // 32*17 floats per chunk
#define REG_FLOATS 544   // one circular region = one chunk
#define LDS_FLOATS 1120  // 2 regions + pad
#define NEGV (-1e30f)
#define LOG2E 1.4426950408889634f
#define LN2 0.6931471805599453f
#define NEGB (NEGV * LOG2E)

__device__ __forceinline__ float hexp2(float x) { return __builtin_amdgcn_exp2f(x); }
__device__ __forceinline__ float hlog2(float x) { return __builtin_amdgcn_logf(x); }

// monotonic float->uint map: a > b (float) <=> fkey(a) > fkey(b) (uint)
__device__ __forceinline__ unsigned fkey(float v) {
    unsigned u = __float_as_uint(v);
    return (u & 0x80000000u) ? ~u : (u | 0x80000000u);
}

typedef const __attribute__((address_space(1))) unsigned int* gas_t;
typedef __attribute__((address_space(3))) unsigned int* las_t;

// 4 waves/block, 1 batch element per wave, circular 2-region LDS lp buffer.
// 8 blocks/CU (18 KB LDS, <=64 VGPR) -> 32 waves/CU: max memory parallelism.
__global__ __launch_bounds__(256, 8) void ctc_main_kernel(
        const float* __restrict__ pred,   // (B, T, C) log-probs
        const float* __restrict__ lab,    // (B, S, C)
        float* __restrict__ out_b) {      // ws[0..B): nll/S per element
    const int wid  = threadIdx.x >> 6;
    const int lane = threadIdx.x & 63;
    const int b = blockIdx.x * 4 + wid;

    __shared__ int   cls_tab[4][NSLOT];
    __shared__ float lps[4][LDS_FLOATS];
    int*   mytab = cls_tab[wid];
    float* mylds = lps[wid];

    const int half = lane >> 5;           // argmax: lanes 0-31 row A, 32-63 row B
    const int li   = lane & 31;

    // ---- Phase A: targets via argmax, 2 passes of 4 row-pairs (low VGPR) ----
    const float4* lr =
        (const float4*)(lab + (size_t)b * S_ * C_ + (size_t)half * C_);
    if (lane == 0) mytab[0] = 0;          // blank class
    #pragma unroll
    for (int pass = 0; pass < 2; ++pass) {
        float4 q[4];
        #pragma unroll
        for (int j = 0; j < 4; ++j) {
            int sp = pass * 4 + j;
            q[j] = lr[(size_t)sp * 2 * (C_ / 4) + li];   // 4 indep 16B loads
        }
        asm volatile("s_waitcnt vmcnt(0)" ::: "memory");
        #pragma unroll
        for (int j = 0; j < 4; ++j) {
            int sp = pass * 4 + j;
            float vals[4] = {q[j].x, q[j].y, q[j].z, q[j].w};
            unsigned long long key = 0;   // fkey(v)<<32 | ~idx: max == (max v, min idx)
            #pragma unroll
            for (int k = 0; k < 4; ++k) {
                unsigned long long kk =
                    ((unsigned long long)fkey(vals[k]) << 32) | (unsigned)(~(li * 4 + k));
                if (kk > key) key = kk;   // strict >, k ascending: first index wins
            }
            #pragma unroll
            for (int off = 16; off >= 1; off >>= 1) {
                unsigned long long ok = __shfl_xor(key, off, 64);  // within half
                if (ok > key) key = ok;
            }
            if (li == 0) mytab[1 + sp * 2 + half] = (int)(~(unsigned)key) & 127;
        }
    }
    asm volatile("s_waitcnt lgkmcnt(0)" ::: "memory");   // cls_tab visible in-wave

    // lane -> DP state constants
    const int l = lane;
    int cidx = 0;
    if (l < L_ && (l & 1)) cidx = 1 + ((l - 1) >> 1);
    const bool has2 = (l >= 1);
    const bool skipv =
        (l < L_ && (l & 1) && l >= 3) && (mytab[cidx] != mytab[cidx - 1]);

    const float* pb = pred + (size_t)b * T_ * C_;

    // ---- staging: chunk c = rows [32c, 32c+32) -> region (c&1), 9 loads ----
    auto stage_chunk = [&](int c) {
        const int roff = (c & 1) * REG_FLOATS;
        #pragma unroll
        for (int i = 0; i < 9; ++i) {
            unsigned e = i * 64 + lane;   // e < 544 under guard
            if (i < 8 || lane < 32) {
                unsigned tl = e / NSLOT;
                unsigned s  = e - tl * NSLOT;
                const float* src = pb + (size_t)(c * CH_ROWS + tl) * C_ + mytab[s];
                __builtin_amdgcn_global_load_lds((gas_t)src,
                                                 (las_t)(mylds + roff + e), 4, 0, 0);
            }
        }
        __builtin_amdgcn_sched_barrier(0);               // pin issue order
    };

    // circular-buffer address of row tt, this lane's class
#define LPOFF(tt) (((((tt) >> 5) & 1) * REG_FLOATS) + (((tt) & 31) * NSLOT) + cidx)

    float beta, lpA, lpB, lpC;
#define SEG(T0, T1)                                                         \
    _Pragma("unroll 4")                                                     \
    for (int t = (T0); t <= (T1); ++t) {                                    \
        float lp = lpA; lpA = lpB; lpB = lpC;                               \
        lpC = mylds[LPOFF(t + 3)];                                          \
        float a2 = __shfl_up(beta, 1, 64);                                  \
        float a3 = __shfl_up(beta, 2, 64);                                  \
        a2 = has2  ? a2 : NEGB;                                             \
        a3 = skipv ? a3 : NEGB;                                             \
        float m = fmaxf(fmaxf(beta, a2), a3);                               \
        float s = hexp2(beta - m) + hexp2(a2 - m) + hexp2(a3 - m);          \
        beta = fmaf(lp, LOG2E, m + hlog2(s));                               \
    }

    stage_chunk(0);                       // rows  0-31  -> region 0
    stage_chunk(1);                       // rows 32-63  -> region 1
    asm volatile("s_waitcnt vmcnt(9)" ::: "memory");     // chunk 0 ready

    beta = (l <= 1) ? mylds[cidx] * LOG2E : NEGB;        // t = 0 (row 0)
    lpA = mylds[LPOFF(1)];
    lpB = mylds[LPOFF(2)];
    lpC = mylds[LPOFF(3)];

    SEG(1, 28)                            // consumes rows 1-28, prefetch to 31
    stage_chunk(2);                       // rows 64-95  -> region 0
    asm volatile("s_waitcnt vmcnt(9)" ::: "memory");     // chunk 1 ready
    SEG(29, 60)                           // prefetch rows 32-63
    stage_chunk(3);                       // rows 96-127 -> region 1
    asm volatile("s_waitcnt vmcnt(9)" ::: "memory");     // chunk 2 ready
    SEG(61, 92)                           // prefetch rows 64-95
    asm volatile("s_waitcnt vmcnt(0)" ::: "memory");     // chunk 3 ready
    SEG(93, 127)                          // prefetch rows 96-127 (+3 dead reads)
#undef SEG
#undef LPOFF

    float b31 = __shfl(beta, L_ - 2, 64);
    float b32 = __shfl(beta, L_ - 1, 64);
    float m2 = fmaxf(b31, b32);
    float nll = -(m2 + hlog2(hexp2(b31 - m2) + hexp2(b32 - m2))) * LN2;
    if (!isfinite(nll)) nll = 0.0f;       // zero_infinity
    if (lane == 0) out_b[b] = nll * (1.0f / (float)S_);
}

__global__ __launch_bounds__(256) void reduce_mean_kernel(
        const float* __restrict__ in, float* __restrict__ out) {
    __shared__ float sm[256];
    const int tid = threadIdx.x;
    float v[16];
    #pragma unroll
    for (int i = 0; i < 16; ++i) v[i] = in[tid + i * 256];
    float s = 0.f;
    #pragma unroll
    for (int i = 0; i < 16; ++i) s += v[i];
    sm[tid] = s;
    __syncthreads();
    for (int w = 128; w >= 1; w >>= 1) {
        if (tid < w) sm[tid] += sm[tid + w];
        __syncthreads();
    }
    if (tid == 0) out[0] = sm[0] / (float)B_;
}

extern "C" void kernel_launch(void* const* d_in, const int* in_sizes, int n_in,
                              void* d_out, int out_size, void* d_ws, size_t ws_size,
                              hipStream_t stream) {
    const float* pred = (const float*)d_in[0];  // (B,T,C) fp32
    const float* lab  = (const float*)d_in[1];  // (B,S,C) fp32
    float* ws = (float*)d_ws;                   // B partial losses
    ctc_main_kernel<<<B_ / 4, 256, 0, stream>>>(pred, lab, ws);
    reduce_mean_kernel<<<1, 256, 0, stream>>>(ws, (float*)d_out);
}

// Round 9
// 56.963 us; speedup vs baseline: 3.7155x; 1.0842x over previous
//
#include <hip/hip_runtime.h>
#include <math.h>
#include <stdint.h>

#define B_ 4096
#define T_ 128
#define S_ 16
#define C_ 128
#define L_ 33            // 2*S+1
#define NSLOT 17         // blank + 16 targets
#define NEGV (-1e30f)
#define LOG2E 1.4426950408889634f
#define LN2 0.6931471805599453f
#define NEGB (NEGV * LOG2E)

__device__ __forceinline__ float hexp2(float x) { return __builtin_amdgcn_exp2f(x); }
__device__ __forceinline__ float hlog2(float x) { return __builtin_amdgcn_logf(x); }

// monotonic float->uint map: a > b (float) <=> fkey(a) > fkey(b) (uint)
__device__ __forceinline__ unsigned fkey(float v) {
    unsigned u = __float_as_uint(v);
    return (u & 0x80000000u) ? ~u : (u | 0x80000000u);
}

typedef const __attribute__((address_space(1))) unsigned int* gas_t;
typedef __attribute__((address_space(3))) unsigned int* las_t;

// 4 waves/block, 1 batch element per wave. FULL pred rows staged coalesced
// into a rolling 16-row LDS window (2 regions x 8 rows x 512B = 8 KB/wave).
// Each global_load_lds (width 16) stages TWO rows: lanes 0-31 row t (16B each),
// lanes 32-63 row t+1; LDS dest = uniform base + lane*16 (linear). This
// replaces the scattered 4B gather (the R4-R8 ~62us floor) with a coalesced
// stream; compulsory bytes rise only ~10% (17 rand classes touch ~7/8 lines).
__global__ __launch_bounds__(256, 4) void ctc_main_kernel(
        const float* __restrict__ pred,   // (B, T, C) log-probs
        const float* __restrict__ lab,    // (B, S, C)
        float* __restrict__ out_b) {      // ws[0..B): nll/S per element
    const int wid  = threadIdx.x >> 6;
    const int lane = threadIdx.x & 63;
    const int b = blockIdx.x * 4 + wid;

    __shared__ int   cls_tab[4][NSLOT];
    __shared__ float lps[4][2048];        // 2 regions x 8 rows x 128 floats
    int*   mytab = cls_tab[wid];
    float* mylds = lps[wid];

    const int half = lane >> 5;           // argmax: lanes 0-31 row A, 32-63 row B
    const int li   = lane & 31;

    // ---- Phase A: targets via argmax, 2 passes of 4 row-pairs ----
    const float4* lr =
        (const float4*)(lab + (size_t)b * S_ * C_ + (size_t)half * C_);
    if (lane == 0) mytab[0] = 0;          // blank class
    #pragma unroll
    for (int pass = 0; pass < 2; ++pass) {
        float4 q[4];
        #pragma unroll
        for (int j = 0; j < 4; ++j) {
            int sp = pass * 4 + j;
            q[j] = lr[(size_t)sp * 2 * (C_ / 4) + li];   // 4 indep 16B loads
        }
        asm volatile("s_waitcnt vmcnt(0)" ::: "memory");
        #pragma unroll
        for (int j = 0; j < 4; ++j) {
            int sp = pass * 4 + j;
            float vals[4] = {q[j].x, q[j].y, q[j].z, q[j].w};
            unsigned long long key = 0;   // fkey(v)<<32 | ~idx: max == (max v, min idx)
            #pragma unroll
            for (int k = 0; k < 4; ++k) {
                unsigned long long kk =
                    ((unsigned long long)fkey(vals[k]) << 32) | (unsigned)(~(li * 4 + k));
                if (kk > key) key = kk;   // strict >, k ascending: first index wins
            }
            #pragma unroll
            for (int off = 16; off >= 1; off >>= 1) {
                unsigned long long ok = __shfl_xor(key, off, 64);  // within half
                if (ok > key) key = ok;
            }
            if (li == 0) mytab[1 + sp * 2 + half] = (int)(~(unsigned)key) & 127;
        }
    }
    asm volatile("s_waitcnt lgkmcnt(0)" ::: "memory");   // cls_tab visible in-wave

    // lane -> DP state constants
    const int l = lane;
    int cidx = 0;
    if (l < L_ && (l & 1)) cidx = 1 + ((l - 1) >> 1);
    const int  cls   = mytab[cidx];       // this lane's class id (0 for blanks)
    const bool has2  = (l >= 1);
    const bool skipv =
        (l < L_ && (l & 1) && l >= 3) && (mytab[cidx] != mytab[cidx - 1]);

    const float* pb = pred + (size_t)b * T_ * C_;

    // ---- staging: chunk c = rows [8c, 8c+8) -> region (c&1), 4 instrs ----
    auto stage_chunk = [&](int c) {
        const int roff = (c & 1) * 1024;  // floats
        #pragma unroll
        for (int j = 0; j < 4; ++j) {
            int row = c * 8 + 2 * j + half;
            const float* src = pb + (size_t)row * C_ + li * 4;   // 16B/lane, coalesced
            __builtin_amdgcn_global_load_lds((gas_t)src,
                                             (las_t)(mylds + roff + j * 256), 16, 0, 0);
        }
        __builtin_amdgcn_sched_barrier(0);               // pin issue order
    };

    // LDS float index of row tt, this lane's class (circular 2-region window)
#define LPOFF(tt) (((((tt) >> 3) & 1) << 10) + ((((tt) >> 1) & 3) << 8) \
                   + (((tt) & 1) << 7) + cls)

    float beta, lpA, lpB, lpC;
#define SEG(T0, T1)                                                         \
    _Pragma("unroll 4")                                                     \
    for (int t = (T0); t <= (T1); ++t) {                                    \
        float lp = lpA; lpA = lpB; lpB = lpC;                               \
        lpC = mylds[LPOFF(t + 3)];                                          \
        float a2 = __shfl_up(beta, 1, 64);                                  \
        float a3 = __shfl_up(beta, 2, 64);                                  \
        a2 = has2  ? a2 : NEGB;                                             \
        a3 = skipv ? a3 : NEGB;                                             \
        float m = fmaxf(fmaxf(beta, a2), a3);                               \
        float s = hexp2(beta - m) + hexp2(a2 - m) + hexp2(a3 - m);          \
        beta = fmaf(lp, LOG2E, m + hlog2(s));                               \
    }

    stage_chunk(0);                       // rows  0-7  -> region 0
    stage_chunk(1);                       // rows  8-15 -> region 1
    asm volatile("s_waitcnt vmcnt(4)" ::: "memory");     // chunk 0 ready

    beta = (l <= 1) ? mylds[cls] * LOG2E : NEGB;         // t = 0 (row 0)
    lpA = mylds[LPOFF(1)];
    lpB = mylds[LPOFF(2)];
    lpC = mylds[LPOFF(3)];

    SEG(1, 4)                             // prefetch rows 4-7 (chunk 0)
    #pragma unroll
    for (int c = 2; c <= 15; ++c) {
        stage_chunk(c);                   // rows 8c..8c+7 -> region (c&1)
        asm volatile("s_waitcnt vmcnt(4)" ::: "memory"); // chunk c-1 ready
        SEG(8 * c - 11, 8 * c - 4)        // prefetch rows 8c-8 .. 8c-1 (chunk c-1)
    }
    asm volatile("s_waitcnt vmcnt(0)" ::: "memory");     // chunk 15 ready
    SEG(117, 127)                         // prefetch rows 120-130 (128-130 dead)
#undef SEG
#undef LPOFF

    float b31 = __shfl(beta, L_ - 2, 64);
    float b32 = __shfl(beta, L_ - 1, 64);
    float m2 = fmaxf(b31, b32);
    float nll = -(m2 + hlog2(hexp2(b31 - m2) + hexp2(b32 - m2))) * LN2;
    if (!isfinite(nll)) nll = 0.0f;       // zero_infinity
    if (lane == 0) out_b[b] = nll * (1.0f / (float)S_);
}

__global__ __launch_bounds__(256) void reduce_mean_kernel(
        const float* __restrict__ in, float* __restrict__ out) {
    __shared__ float sm[256];
    const int tid = threadIdx.x;
    float v[16];
    #pragma unroll
    for (int i = 0; i < 16; ++i) v[i] = in[tid + i * 256];
    float s = 0.f;
    #pragma unroll
    for (int i = 0; i < 16; ++i) s += v[i];
    sm[tid] = s;
    __syncthreads();
    for (int w = 128; w >= 1; w >>= 1) {
        if (tid < w) sm[tid] += sm[tid + w];
        __syncthreads();
    }
    if (tid == 0) out[0] = sm[0] / (float)B_;
}

extern "C" void kernel_launch(void* const* d_in, const int* in_sizes, int n_in,
                              void* d_out, int out_size, void* d_ws, size_t ws_size,
                              hipStream_t stream) {
    const float* pred = (const float*)d_in[0];  // (B,T,C) fp32
    const float* lab  = (const float*)d_in[1];  // (B,S,C) fp32
    float* ws = (float*)d_ws;                   // B partial losses
    ctc_main_kernel<<<B_ / 4, 256, 0, stream>>>(pred, lab, ws);
    reduce_mean_kernel<<<1, 256, 0, stream>>>(ws, (float*)d_out);
}